// Round 1
// baseline (8118.254 us; speedup 1.0000x reference)
//
#include <hip/hip_runtime.h>

// ResNet4D forward, f32 direct convolutions.
// Layout for all activations: [C][T][D][H][W], C outermost, f32.

__device__ __forceinline__ int imin(int a, int b) { return a < b ? a : b; }
__device__ __forceinline__ int imax(int a, int b) { return a > b ? a : b; }

// ---------------- conv1: x (36^4, 1ch), w (7,64,1,7,7,7), stride 2, pad 3, relu ----------------
// out (64, 18^4). Each thread: one output position, 16 output channels (grid.y = 4 chunks).
__global__ void conv1_kernel(const float* __restrict__ x, const float* __restrict__ w,
                             float* __restrict__ out) {
    const int O4 = 18 * 18 * 18 * 18; // 104976
    int pos = blockIdx.x * blockDim.x + threadIdx.x;
    if (pos >= O4) return;
    int co0 = blockIdx.y * 16;

    int t = pos;
    int ow = t % 18; t /= 18;
    int oh = t % 18; t /= 18;
    int od = t % 18; t /= 18;
    int ot = t;

    int bt = 2 * ot - 3, bd = 2 * od - 3, bh = 2 * oh - 3, bw = 2 * ow - 3;
    int lt0 = imax(0, -bt), lt1 = imin(6, 35 - bt);
    int ld0 = imax(0, -bd), ld1 = imin(6, 35 - bd);
    int lh0 = imax(0, -bh), lh1 = imin(6, 35 - bh);
    int lw0 = imax(0, -bw), lw1 = imin(6, 35 - bw);

    float acc[16];
#pragma unroll
    for (int c = 0; c < 16; ++c) acc[c] = 0.f;

    for (int kt = lt0; kt <= lt1; ++kt) {
        const float* wt = w + (kt * 64 + co0) * 343;
        const float* xt = x + (bt + kt) * (36 * 36 * 36);
        for (int kd = ld0; kd <= ld1; ++kd) {
            const float* xd = xt + (bd + kd) * (36 * 36);
            const float* wd = wt + kd * 49;
            for (int kh = lh0; kh <= lh1; ++kh) {
                const float* xh = xd + (bh + kh) * 36;
                const float* wh = wd + kh * 7;
                for (int kw = lw0; kw <= lw1; ++kw) {
                    float xv = xh[bw + kw];
                    const float* wp = wh + kw;
#pragma unroll
                    for (int c = 0; c < 16; ++c)
                        acc[c] = fmaf(xv, wp[c * 343], acc[c]);
                }
            }
        }
    }
#pragma unroll
    for (int c = 0; c < 16; ++c)
        out[(size_t)(co0 + c) * O4 + pos] = fmaxf(acc[c], 0.f);
}

// ---------------- maxpool 3^4 stride 2 pad 1: (64,18^4) -> (64,9^4) ----------------
__global__ void maxpool_kernel(const float* __restrict__ in, float* __restrict__ out) {
    const int T = 18, T4 = 18 * 18 * 18 * 18, O4 = 9 * 9 * 9 * 9;
    int idx = blockIdx.x * blockDim.x + threadIdx.x;
    if (idx >= 64 * O4) return;
    int co = idx / O4, p = idx % O4;
    int ow = p % 9; int t = p / 9;
    int oh = t % 9; t /= 9;
    int od = t % 9; t /= 9;
    int ot = t;
    const float* base = in + (size_t)co * T4;
    float m = -1e30f;
    for (int kt = 0; kt < 3; ++kt) { int it = 2 * ot + kt - 1; if (it < 0 || it >= T) continue;
        for (int kd = 0; kd < 3; ++kd) { int id = 2 * od + kd - 1; if (id < 0 || id >= T) continue;
            for (int kh = 0; kh < 3; ++kh) { int ih = 2 * oh + kh - 1; if (ih < 0 || ih >= T) continue;
                for (int kw = 0; kw < 3; ++kw) { int iw = 2 * ow + kw - 1; if (iw < 0 || iw >= T) continue;
                    m = fmaxf(m, base[((it * T + id) * T + ih) * T + iw]);
                }
            }
        }
    }
    out[idx] = m;
}

// ---------------- generic residual 4D conv: K=3 (T dim), 3x3x3 spatial, pad 1 ----------------
// w (3,Co,Ci,3,3,3), bias (3,Co) with per-valid-i accumulation, optional residual, relu.
// ci-split across `split = 1<<lsplit` consecutive threads + shuffle reduce.
__global__ void convR_kernel(const float* __restrict__ in, const float* __restrict__ w,
                             const float* __restrict__ bias, const float* __restrict__ res,
                             float* __restrict__ out,
                             int Ci, int Co, int T, int O, int stride, int lsplit, int total_out) {
    int g = blockIdx.x * blockDim.x + threadIdx.x;
    int out_idx = g >> lsplit;
    if (out_idx >= total_out) return;
    int split = 1 << lsplit;
    int sub = g & (split - 1);

    int T2 = T * T, T3 = T2 * T, T4 = T3 * T;
    int O4 = O * O * O * O;
    int co = out_idx / O4;
    int p = out_idx % O4;
    int ow = p % O; int t = p / O;
    int oh = t % O; t /= O;
    int od = t % O; t /= O;
    int ot = t;

    int cchunk = Ci >> lsplit;
    int ci0 = sub * cchunk;

    float acc = 0.f;
    for (int i = 0; i < 3; ++i) {
        int jt = ot * stride + i - 1;
        if (jt < 0 || jt >= T) continue;
        const float* wi = w + ((size_t)(i * Co + co) * Ci + ci0) * 27;
        const float* xi = in + (size_t)ci0 * T4 + jt * T3;
        for (int kd = 0; kd < 3; ++kd) {
            int id = od * stride + kd - 1; if (id < 0 || id >= T) continue;
            for (int kh = 0; kh < 3; ++kh) {
                int ih = oh * stride + kh - 1; if (ih < 0 || ih >= T) continue;
                for (int kw = 0; kw < 3; ++kw) {
                    int iw = ow * stride + kw - 1; if (iw < 0 || iw >= T) continue;
                    const float* xp = xi + id * T2 + ih * T + iw;
                    const float* wp = wi + kd * 9 + kh * 3 + kw;
#pragma unroll 4
                    for (int cc = 0; cc < cchunk; ++cc) {
                        acc = fmaf(*xp, *wp, acc);
                        xp += T4; wp += 27;
                    }
                }
            }
        }
    }
    // reduce partial sums across the split group (consecutive lanes, 64 % split == 0)
    for (int off = split >> 1; off > 0; off >>= 1)
        acc += __shfl_xor(acc, off, 64);

    if (sub == 0) {
        float v = acc;
        if (bias) {
            for (int i = 0; i < 3; ++i) {
                int jt = ot * stride + i - 1;
                if (jt >= 0 && jt < T) v += bias[i * Co + co];
            }
        }
        if (res) v += res[out_idx];
        out[out_idx] = fmaxf(v, 0.f);
    }
}

// ---------------- downsample 1x1x1x1 conv, stride 2, pad 0, no bias, no relu ----------------
__global__ void dwconv_kernel(const float* __restrict__ in, const float* __restrict__ w,
                              float* __restrict__ out, int Ci, int Co, int T, int O,
                              int lsplit, int total_out) {
    int g = blockIdx.x * blockDim.x + threadIdx.x;
    int out_idx = g >> lsplit;
    if (out_idx >= total_out) return;
    int split = 1 << lsplit;
    int sub = g & (split - 1);

    int T4 = T * T * T * T;
    int O4 = O * O * O * O;
    int co = out_idx / O4;
    int p = out_idx % O4;
    int ow = p % O; int t = p / O;
    int oh = t % O; t /= O;
    int od = t % O; t /= O;
    int ot = t;
    int ip = ((2 * ot * T + 2 * od) * T + 2 * oh) * T + 2 * ow;

    int cchunk = Ci >> lsplit;
    int ci0 = sub * cchunk;
    const float* xp = in + (size_t)ci0 * T4 + ip;
    const float* wp = w + (size_t)co * Ci + ci0;
    float acc = 0.f;
#pragma unroll 4
    for (int cc = 0; cc < cchunk; ++cc) {
        acc = fmaf(xp[0], wp[0], acc);
        xp += T4; wp += 1;
    }
    for (int off = split >> 1; off > 0; off >>= 1)
        acc += __shfl_xor(acc, off, 64);
    if (sub == 0) out[out_idx] = acc;
}

// ---------------- avgpool 2^4 (16 elems/channel) + FC (512 -> 1) ----------------
__global__ void avgfc_kernel(const float* __restrict__ in, const float* __restrict__ fw,
                             const float* __restrict__ fb, float* __restrict__ out) {
    __shared__ float ls[8];
    int t = threadIdx.x; // 512 threads
    float s = 0.f;
#pragma unroll
    for (int k = 0; k < 16; ++k) s += in[t * 16 + k];
    s = s * (1.f / 16.f) * fw[t];
    for (int off = 32; off > 0; off >>= 1) s += __shfl_xor(s, off, 64);
    if ((t & 63) == 0) ls[t >> 6] = s;
    __syncthreads();
    if (t == 0) {
        float tot = 0.f;
#pragma unroll
        for (int i = 0; i < 8; ++i) tot += ls[i];
        out[0] = tot + fb[0];
    }
}

extern "C" void kernel_launch(void* const* d_in, const int* in_sizes, int n_in,
                              void* d_out, int out_size, void* d_ws, size_t ws_size,
                              hipStream_t stream) {
    const float* x       = (const float*)d_in[0];
    const float* conv1_w = (const float*)d_in[1];
    const float* l1_w1 = (const float*)d_in[2];
    const float* l1_b1 = (const float*)d_in[3];
    const float* l1_w2 = (const float*)d_in[4];
    const float* l1_b2 = (const float*)d_in[5];
    const float* l2_w1 = (const float*)d_in[6];
    const float* l2_b1 = (const float*)d_in[7];
    const float* l2_w2 = (const float*)d_in[8];
    const float* l2_b2 = (const float*)d_in[9];
    const float* l2_dw = (const float*)d_in[10];
    const float* l3_w1 = (const float*)d_in[11];
    const float* l3_b1 = (const float*)d_in[12];
    const float* l3_w2 = (const float*)d_in[13];
    const float* l3_b2 = (const float*)d_in[14];
    const float* l3_dw = (const float*)d_in[15];
    const float* l4_w1 = (const float*)d_in[16];
    const float* l4_b1 = (const float*)d_in[17];
    const float* l4_w2 = (const float*)d_in[18];
    const float* l4_b2 = (const float*)d_in[19];
    const float* l4_dw = (const float*)d_in[20];
    const float* fc_w  = (const float*)d_in[21];
    const float* fc_b  = (const float*)d_in[22];
    float* outp = (float*)d_out;

    float* ws = (float*)d_ws;
    float* A = ws;                 // conv1 out: 64*18^4 = 6,718,464
    float* B = A + 6718464;        // 419,904 each below
    float* C = B + 419904;
    float* D = C + 419904;
    float* E = D + 419904;

    // conv1 + relu: x -> A (64, 18^4)
    {
        dim3 grid((104976 + 255) / 256, 4);
        conv1_kernel<<<grid, 256, 0, stream>>>(x, conv1_w, A);
    }
    // maxpool: A -> B (64, 9^4)
    {
        int tot = 64 * 6561;
        maxpool_kernel<<<(tot + 255) / 256, 256, 0, stream>>>(A, B);
    }

    auto convR = [&](const float* in, const float* w, const float* b, const float* res,
                     float* o, int Ci, int Co, int T, int O, int stride, int lsplit) {
        int total_out = Co * O * O * O * O;
        long total_thr = (long)total_out << lsplit;
        int blocks = (int)((total_thr + 255) / 256);
        convR_kernel<<<blocks, 256, 0, stream>>>(in, w, b, res, o, Ci, Co, T, O, stride,
                                                 lsplit, total_out);
    };
    auto dwconv = [&](const float* in, const float* w, float* o,
                      int Ci, int Co, int T, int O, int lsplit) {
        int total_out = Co * O * O * O * O;
        long total_thr = (long)total_out << lsplit;
        int blocks = (int)((total_thr + 255) / 256);
        dwconv_kernel<<<blocks, 256, 0, stream>>>(in, w, o, Ci, Co, T, O, lsplit, total_out);
    };

    // layer1 (64 -> 64, T=9, stride 1, identity residual): in B -> out D
    convR(B, l1_w1, l1_b1, nullptr, C, 64, 64, 9, 9, 1, 0);
    convR(C, l1_w2, l1_b2, B,       D, 64, 64, 9, 9, 1, 0);

    // layer2 (64 -> 128, T=9 -> O=5, stride 2, dw residual): in D -> out E
    convR(D, l2_w1, l2_b1, nullptr, C, 64, 128, 9, 5, 2, 2);
    dwconv(D, l2_dw, B, 64, 128, 9, 5, 1);
    convR(C, l2_w2, l2_b2, B,       E, 128, 128, 5, 5, 1, 2);

    // layer3 (128 -> 256, T=5 -> O=3): in E -> out D
    convR(E, l3_w1, l3_b1, nullptr, C, 128, 256, 5, 3, 2, 4);
    dwconv(E, l3_dw, B, 128, 256, 5, 3, 3);
    convR(C, l3_w2, l3_b2, B,       D, 256, 256, 3, 3, 1, 4);

    // layer4 (256 -> 512, T=3 -> O=2): in D -> out E
    convR(D, l4_w1, l4_b1, nullptr, C, 256, 512, 3, 2, 2, 5);
    dwconv(D, l4_dw, B, 256, 512, 3, 2, 4);
    convR(C, l4_w2, l4_b2, B,       E, 512, 512, 2, 2, 1, 5);

    // avgpool + fc -> scalar
    avgfc_kernel<<<1, 512, 0, stream>>>(E, fc_w, fc_b, outp);
}

// Round 2
// 5917.221 us; speedup vs baseline: 1.3720x; 1.3720x over previous
//
#include <hip/hip_runtime.h>

__device__ __forceinline__ int imin(int a, int b) { return a < b ? a : b; }
__device__ __forceinline__ int imax(int a, int b) { return a > b ? a : b; }

// ---------------- batched 2D transpose: in[b][R][C] -> out[b][C][R] ----------------
__global__ void transpose_bk(const float* __restrict__ in, float* __restrict__ out,
                             int R, int C) {
    __shared__ float tile[32][33];
    size_t base = (size_t)blockIdx.z * R * C;
    int c0 = blockIdx.x * 32, r0 = blockIdx.y * 32;
    int tx = threadIdx.x, ty = threadIdx.y; // 32x8
#pragma unroll
    for (int i = 0; i < 32; i += 8) {
        int r = r0 + ty + i, c = c0 + tx;
        if (r < R && c < C) tile[ty + i][tx] = in[base + (size_t)r * C + c];
    }
    __syncthreads();
#pragma unroll
    for (int i = 0; i < 32; i += 8) {
        int c = c0 + ty + i, r = r0 + tx;
        if (c < C && r < R) out[base + (size_t)c * R + r] = tile[tx][ty + i];
    }
}

// ---------------- conv1 v2: x (1,36^4), Wt [7][343][64] (co-innermost), stride2 pad3, relu --
// thread: 3 ow x 8 co. grid.y = 8 co chunks.
__global__ void conv1_kernel2(const float* __restrict__ x, const float* __restrict__ wt,
                              float* __restrict__ out) {
    int t = blockIdx.x * 256 + threadIdx.x;
    if (t >= 18 * 18 * 18 * 6) return;
    int co0 = blockIdx.y * 8;
    int owg = t % 6; t /= 6;
    int oh = t % 18; t /= 18;
    int od = t % 18; t /= 18;
    int ot = t;
    int ow0 = owg * 3;

    int bt = 2 * ot - 3, bd = 2 * od - 3, bh = 2 * oh - 3, bw = 2 * ow0 - 3;
    int lt0 = imax(0, -bt), lt1 = imin(6, 35 - bt);
    int ld0 = imax(0, -bd), ld1 = imin(6, 35 - bd);
    int lh0 = imax(0, -bh), lh1 = imin(6, 35 - bh);

    float acc[8][3];
#pragma unroll
    for (int c = 0; c < 8; ++c)
#pragma unroll
        for (int q = 0; q < 3; ++q) acc[c][q] = 0.f;

    for (int kt = lt0; kt <= lt1; ++kt) {
        const float* xt = x + (bt + kt) * 46656;
        const float* wkt = wt + kt * 343 * 64 + co0;
        for (int kd = ld0; kd <= ld1; ++kd) {
            const float* xd = xt + (bd + kd) * 1296;
            for (int kh = lh0; kh <= lh1; ++kh) {
                const float* xrow = xd + (bh + kh) * 36;
                float xv[11];
#pragma unroll
                for (int j = 0; j < 11; ++j) {
                    int iw = bw + j;
                    xv[j] = ((unsigned)iw < 36u) ? xrow[iw] : 0.f;
                }
                const float* wrow = wkt + (kd * 49 + kh * 7) * 64;
#pragma unroll
                for (int kw = 0; kw < 7; ++kw) {
                    float4 wa = *(const float4*)(wrow + kw * 64);
                    float4 wb = *(const float4*)(wrow + kw * 64 + 4);
#pragma unroll
                    for (int q = 0; q < 3; ++q) {
                        float xq = xv[2 * q + kw];
                        acc[0][q] = fmaf(xq, wa.x, acc[0][q]);
                        acc[1][q] = fmaf(xq, wa.y, acc[1][q]);
                        acc[2][q] = fmaf(xq, wa.z, acc[2][q]);
                        acc[3][q] = fmaf(xq, wa.w, acc[3][q]);
                        acc[4][q] = fmaf(xq, wb.x, acc[4][q]);
                        acc[5][q] = fmaf(xq, wb.y, acc[5][q]);
                        acc[6][q] = fmaf(xq, wb.z, acc[6][q]);
                        acc[7][q] = fmaf(xq, wb.w, acc[7][q]);
                    }
                }
            }
        }
    }
    int pos0 = ((ot * 18 + od) * 18 + oh) * 18 + ow0;
#pragma unroll
    for (int c = 0; c < 8; ++c)
#pragma unroll
        for (int q = 0; q < 3; ++q)
            out[(size_t)(co0 + c) * 104976 + pos0 + q] = fmaxf(acc[c][q], 0.f);
}

// ---------------- maxpool 3^4 stride 2 pad 1: (64,18^4) -> (64,9^4) ----------------
__global__ void maxpool_kernel(const float* __restrict__ in, float* __restrict__ out) {
    const int T = 18, T4 = 18 * 18 * 18 * 18, O4 = 9 * 9 * 9 * 9;
    int idx = blockIdx.x * blockDim.x + threadIdx.x;
    if (idx >= 64 * O4) return;
    int co = idx / O4, p = idx % O4;
    int ow = p % 9; int t = p / 9;
    int oh = t % 9; t /= 9;
    int od = t % 9; t /= 9;
    int ot = t;
    const float* base = in + (size_t)co * T4;
    float m = -1e30f;
    for (int kt = 0; kt < 3; ++kt) { int it = 2 * ot + kt - 1; if (it < 0 || it >= T) continue;
        for (int kd = 0; kd < 3; ++kd) { int id = 2 * od + kd - 1; if (id < 0 || id >= T) continue;
            for (int kh = 0; kh < 3; ++kh) { int ih = 2 * oh + kh - 1; if (ih < 0 || ih >= T) continue;
                for (int kw = 0; kw < 3; ++kw) { int iw = 2 * ow + kw - 1; if (iw < 0 || iw >= T) continue;
                    m = fmaxf(m, base[((it * T + id) * T + ih) * T + iw]);
                }
            }
        }
    }
    out[idx] = m;
}

// ---------------- residual conv, 8-co register block, ci-split + shfl reduce ----------------
// TW=1: w is transposed [i][ci][27][Co]; TW=0: original [i][Co][Ci][27].
template <int TW>
__global__ void convR2_kernel(const float* __restrict__ in, const float* __restrict__ w,
                              const float* __restrict__ bias, const float* __restrict__ res,
                              float* __restrict__ out,
                              int Ci, int Co, int T, int O, int stride, int lsplit,
                              int total_r) {
    int g = blockIdx.x * blockDim.x + threadIdx.x;
    int sub = g & ((1 << lsplit) - 1);
    int r = g >> lsplit;
    if (r >= total_r) return;
    int O4 = O * O * O * O;
    int cog = r / O4, pos = r % O4;
    int co0 = cog * 8;
    int ow = pos % O; int tt = pos / O;
    int oh = tt % O; tt /= O;
    int od = tt % O; tt /= O;
    int ot = tt;
    int T2 = T * T, T3 = T2 * T, T4 = T3 * T;
    int cchunk = Ci >> lsplit;
    int ci0 = sub * cchunk;

    float acc[8];
#pragma unroll
    for (int c = 0; c < 8; ++c) acc[c] = 0.f;

    for (int i = 0; i < 3; ++i) {
        int jt = ot * stride + i - 1;
        if ((unsigned)jt >= (unsigned)T) continue;
        for (int kd = 0; kd < 3; ++kd) {
            int id = od * stride + kd - 1; if ((unsigned)id >= (unsigned)T) continue;
            for (int kh = 0; kh < 3; ++kh) {
                int ih = oh * stride + kh - 1; if ((unsigned)ih >= (unsigned)T) continue;
                for (int kw = 0; kw < 3; ++kw) {
                    int iw = ow * stride + kw - 1; if ((unsigned)iw >= (unsigned)T) continue;
                    int tap = kd * 9 + kh * 3 + kw;
                    const float* xp = in + (size_t)ci0 * T4 + ((jt * T + id) * T + ih) * T + iw;
                    if (TW) {
                        const float* wp = w + ((size_t)(i * Ci + ci0) * 27 + tap) * Co + co0;
                        size_t wstride = (size_t)27 * Co;
#pragma unroll 4
                        for (int cc = 0; cc < cchunk; ++cc) {
                            float xv = xp[(size_t)cc * T4];
                            float4 wa = *(const float4*)(wp + cc * wstride);
                            float4 wb = *(const float4*)(wp + cc * wstride + 4);
                            acc[0] = fmaf(xv, wa.x, acc[0]);
                            acc[1] = fmaf(xv, wa.y, acc[1]);
                            acc[2] = fmaf(xv, wa.z, acc[2]);
                            acc[3] = fmaf(xv, wa.w, acc[3]);
                            acc[4] = fmaf(xv, wb.x, acc[4]);
                            acc[5] = fmaf(xv, wb.y, acc[5]);
                            acc[6] = fmaf(xv, wb.z, acc[6]);
                            acc[7] = fmaf(xv, wb.w, acc[7]);
                        }
                    } else {
                        const float* wp = w + ((size_t)(i * Co + co0) * Ci + ci0) * 27 + tap;
                        int ws27 = Ci * 27;
#pragma unroll 4
                        for (int cc = 0; cc < cchunk; ++cc) {
                            float xv = xp[(size_t)cc * T4];
#pragma unroll
                            for (int c = 0; c < 8; ++c)
                                acc[c] = fmaf(xv, wp[c * ws27 + cc * 27], acc[c]);
                        }
                    }
                }
            }
        }
    }

    int split = 1 << lsplit;
    for (int off = split >> 1; off > 0; off >>= 1)
#pragma unroll
        for (int c = 0; c < 8; ++c) acc[c] += __shfl_xor(acc[c], off, 64);

    if (sub == 0) {
#pragma unroll
        for (int c = 0; c < 8; ++c) {
            float v = acc[c];
            if (bias) {
                for (int i = 0; i < 3; ++i) {
                    int jt = ot * stride + i - 1;
                    if ((unsigned)jt < (unsigned)T) v += bias[i * Co + co0 + c];
                }
            }
            int oidx = (co0 + c) * O4 + pos;
            if (res) v += res[oidx];
            out[oidx] = fmaxf(v, 0.f);
        }
    }
}

// ---------------- downsample 1x1x1x1 conv, stride 2 ----------------
__global__ void dwconv_kernel(const float* __restrict__ in, const float* __restrict__ w,
                              float* __restrict__ out, int Ci, int Co, int T, int O,
                              int lsplit, int total_out) {
    int g = blockIdx.x * blockDim.x + threadIdx.x;
    int out_idx = g >> lsplit;
    if (out_idx >= total_out) return;
    int split = 1 << lsplit;
    int sub = g & (split - 1);

    int T4 = T * T * T * T;
    int O4 = O * O * O * O;
    int co = out_idx / O4;
    int p = out_idx % O4;
    int ow = p % O; int t = p / O;
    int oh = t % O; t /= O;
    int od = t % O; t /= O;
    int ot = t;
    int ip = ((2 * ot * T + 2 * od) * T + 2 * oh) * T + 2 * ow;

    int cchunk = Ci >> lsplit;
    int ci0 = sub * cchunk;
    const float* xp = in + (size_t)ci0 * T4 + ip;
    const float* wp = w + (size_t)co * Ci + ci0;
    float acc = 0.f;
#pragma unroll 4
    for (int cc = 0; cc < cchunk; ++cc) {
        acc = fmaf(xp[0], wp[0], acc);
        xp += T4; wp += 1;
    }
    for (int off = split >> 1; off > 0; off >>= 1)
        acc += __shfl_xor(acc, off, 64);
    if (sub == 0) out[out_idx] = acc;
}

// ---------------- avgpool 2^4 + FC (512 -> 1) ----------------
__global__ void avgfc_kernel(const float* __restrict__ in, const float* __restrict__ fw,
                             const float* __restrict__ fb, float* __restrict__ out) {
    __shared__ float ls[8];
    int t = threadIdx.x; // 512 threads
    float s = 0.f;
#pragma unroll
    for (int k = 0; k < 16; ++k) s += in[t * 16 + k];
    s = s * (1.f / 16.f) * fw[t];
    for (int off = 32; off > 0; off >>= 1) s += __shfl_xor(s, off, 64);
    if ((t & 63) == 0) ls[t >> 6] = s;
    __syncthreads();
    if (t == 0) {
        float tot = 0.f;
#pragma unroll
        for (int i = 0; i < 8; ++i) tot += ls[i];
        out[0] = tot + fb[0];
    }
}

extern "C" void kernel_launch(void* const* d_in, const int* in_sizes, int n_in,
                              void* d_out, int out_size, void* d_ws, size_t ws_size,
                              hipStream_t stream) {
    const float* x       = (const float*)d_in[0];
    const float* conv1_w = (const float*)d_in[1];
    const float* l1_w1 = (const float*)d_in[2];
    const float* l1_b1 = (const float*)d_in[3];
    const float* l1_w2 = (const float*)d_in[4];
    const float* l1_b2 = (const float*)d_in[5];
    const float* l2_w1 = (const float*)d_in[6];
    const float* l2_b1 = (const float*)d_in[7];
    const float* l2_w2 = (const float*)d_in[8];
    const float* l2_b2 = (const float*)d_in[9];
    const float* l2_dw = (const float*)d_in[10];
    const float* l3_w1 = (const float*)d_in[11];
    const float* l3_b1 = (const float*)d_in[12];
    const float* l3_w2 = (const float*)d_in[13];
    const float* l3_b2 = (const float*)d_in[14];
    const float* l3_dw = (const float*)d_in[15];
    const float* l4_w1 = (const float*)d_in[16];
    const float* l4_b1 = (const float*)d_in[17];
    const float* l4_w2 = (const float*)d_in[18];
    const float* l4_b2 = (const float*)d_in[19];
    const float* l4_dw = (const float*)d_in[20];
    const float* fc_w  = (const float*)d_in[21];
    const float* fc_b  = (const float*)d_in[22];
    float* outp = (float*)d_out;

    float* ws = (float*)d_ws;
    float* A   = ws;                    // 6,718,464
    float* B   = A + 6718464;           // 419,904 each
    float* C   = B + 419904;
    float* D   = C + 419904;
    float* E   = D + 419904;
    float* Wt1 = E + 419904;            // 7*343*64   = 153,664
    float* T11 = Wt1 + 153664;          // 3*1728*64  = 331,776
    float* T12 = T11 + 331776;
    float* T21 = T12 + 331776;          // 3*1728*128 = 663,552
    float* T22 = T21 + 663552;          // 3*3456*128 = 1,327,104
    float* T31 = T22 + 1327104;         // 3*3456*256 = 2,654,208
    float* T32 = T31 + 2654208;         // 3*6912*256 = 5,308,416

    dim3 tb(32, 8);
    // weight transposes (co-innermost layouts)
    transpose_bk<<<dim3(11, 2, 7),  tb, 0, stream>>>(conv1_w, Wt1, 64, 343);
    transpose_bk<<<dim3(54, 2, 3),  tb, 0, stream>>>(l1_w1, T11, 64, 1728);
    transpose_bk<<<dim3(54, 2, 3),  tb, 0, stream>>>(l1_w2, T12, 64, 1728);
    transpose_bk<<<dim3(54, 4, 3),  tb, 0, stream>>>(l2_w1, T21, 128, 1728);
    transpose_bk<<<dim3(108, 4, 3), tb, 0, stream>>>(l2_w2, T22, 128, 3456);
    transpose_bk<<<dim3(108, 8, 3), tb, 0, stream>>>(l3_w1, T31, 256, 3456);
    transpose_bk<<<dim3(216, 8, 3), tb, 0, stream>>>(l3_w2, T32, 256, 6912);

    // conv1 + relu: x -> A (64, 18^4)
    conv1_kernel2<<<dim3(137, 8), 256, 0, stream>>>(x, Wt1, A);
    // maxpool: A -> B (64, 9^4)
    maxpool_kernel<<<(64 * 6561 + 255) / 256, 256, 0, stream>>>(A, B);

    auto convR2 = [&](const float* in, const float* w, const float* b, const float* res,
                      float* o, int Ci, int Co, int T, int O, int stride, int lsplit, bool tw) {
        int O4 = O * O * O * O;
        int total_r = (Co / 8) * O4;
        long thr = (long)total_r << lsplit;
        int blocks = (int)((thr + 255) / 256);
        if (tw)
            convR2_kernel<1><<<blocks, 256, 0, stream>>>(in, w, b, res, o, Ci, Co, T, O,
                                                         stride, lsplit, total_r);
        else
            convR2_kernel<0><<<blocks, 256, 0, stream>>>(in, w, b, res, o, Ci, Co, T, O,
                                                         stride, lsplit, total_r);
    };
    auto dwconv = [&](const float* in, const float* w, float* o,
                      int Ci, int Co, int T, int O, int lsplit) {
        int total_out = Co * O * O * O * O;
        long thr = (long)total_out << lsplit;
        int blocks = (int)((thr + 255) / 256);
        dwconv_kernel<<<blocks, 256, 0, stream>>>(in, w, o, Ci, Co, T, O, lsplit, total_out);
    };

    // layer1 (64->64, T=9, s1, identity res): B -> D
    convR2(B, T11, l1_b1, nullptr, C, 64, 64, 9, 9, 1, 2, true);
    convR2(C, T12, l1_b2, B,       D, 64, 64, 9, 9, 1, 2, true);

    // layer2 (64->128, 9->5, s2): D -> E
    convR2(D, T21, l2_b1, nullptr, C, 64, 128, 9, 5, 2, 3, true);
    dwconv(D, l2_dw, B, 64, 128, 9, 5, 1);
    convR2(C, T22, l2_b2, B,       E, 128, 128, 5, 5, 1, 3, true);

    // layer3 (128->256, 5->3, s2): E -> D
    convR2(E, T31, l3_b1, nullptr, C, 128, 256, 5, 3, 2, 5, true);
    dwconv(E, l3_dw, B, 128, 256, 5, 3, 3);
    convR2(C, T32, l3_b2, B,       D, 256, 256, 3, 3, 1, 5, true);

    // layer4 (256->512, 3->2, s2, original weight layout): D -> E
    convR2(D, l4_w1, l4_b1, nullptr, C, 256, 512, 3, 2, 2, 6, false);
    dwconv(D, l4_dw, B, 256, 512, 3, 2, 4);
    convR2(C, l4_w2, l4_b2, B,     E, 512, 512, 2, 2, 1, 6, false);

    // avgpool + fc -> scalar
    avgfc_kernel<<<1, 512, 0, stream>>>(E, fc_w, fc_b, outp);
}

// Round 3
// 2171.604 us; speedup vs baseline: 3.7384x; 2.7248x over previous
//
#include <hip/hip_runtime.h>

typedef __bf16 bf16x8 __attribute__((ext_vector_type(8)));
typedef float f32x4 __attribute__((ext_vector_type(4)));
typedef unsigned short ushortT;

__device__ __forceinline__ int imin(int a, int b) { return a < b ? a : b; }
__device__ __forceinline__ int imax(int a, int b) { return a > b ? a : b; }

__device__ __forceinline__ unsigned short f2bf(float f) {
    unsigned u = __float_as_uint(f);
    u += 0x7fffu + ((u >> 16) & 1u);
    return (unsigned short)(u >> 16);
}
__device__ __forceinline__ float bf2f(unsigned short h) {
    return __uint_as_float((unsigned)h << 16);
}

// ---------------- batched 2D transpose (conv1 weights): in[b][R][C] -> out[b][C][R] --------
__global__ void transpose_bk(const float* __restrict__ in, float* __restrict__ out,
                             int R, int C) {
    __shared__ float tile[32][33];
    size_t base = (size_t)blockIdx.z * R * C;
    int c0 = blockIdx.x * 32, r0 = blockIdx.y * 32;
    int tx = threadIdx.x, ty = threadIdx.y; // 32x8
#pragma unroll
    for (int i = 0; i < 32; i += 8) {
        int r = r0 + ty + i, c = c0 + tx;
        if (r < R && c < C) tile[ty + i][tx] = in[base + (size_t)r * C + c];
    }
    __syncthreads();
#pragma unroll
    for (int i = 0; i < 32; i += 8) {
        int c = c0 + ty + i, r = r0 + tx;
        if (c < C && r < R) out[base + (size_t)c * R + r] = tile[tx][ty + i];
    }
}

// ---------------- conv1: x (1,36^4), Wt [7][343][64], stride2 pad3, relu ----------------
__global__ void conv1_kernel2(const float* __restrict__ x, const float* __restrict__ wt,
                              float* __restrict__ out) {
    int t = blockIdx.x * 256 + threadIdx.x;
    if (t >= 18 * 18 * 18 * 6) return;
    int co0 = blockIdx.y * 8;
    int owg = t % 6; t /= 6;
    int oh = t % 18; t /= 18;
    int od = t % 18; t /= 18;
    int ot = t;
    int ow0 = owg * 3;

    int bt = 2 * ot - 3, bd = 2 * od - 3, bh = 2 * oh - 3, bw = 2 * ow0 - 3;
    int lt0 = imax(0, -bt), lt1 = imin(6, 35 - bt);
    int ld0 = imax(0, -bd), ld1 = imin(6, 35 - bd);
    int lh0 = imax(0, -bh), lh1 = imin(6, 35 - bh);

    float acc[8][3];
#pragma unroll
    for (int c = 0; c < 8; ++c)
#pragma unroll
        for (int q = 0; q < 3; ++q) acc[c][q] = 0.f;

    for (int kt = lt0; kt <= lt1; ++kt) {
        const float* xt = x + (bt + kt) * 46656;
        const float* wkt = wt + kt * 343 * 64 + co0;
        for (int kd = ld0; kd <= ld1; ++kd) {
            const float* xd = xt + (bd + kd) * 1296;
            for (int kh = lh0; kh <= lh1; ++kh) {
                const float* xrow = xd + (bh + kh) * 36;
                float xv[11];
#pragma unroll
                for (int j = 0; j < 11; ++j) {
                    int iw = bw + j;
                    xv[j] = ((unsigned)iw < 36u) ? xrow[iw] : 0.f;
                }
                const float* wrow = wkt + (kd * 49 + kh * 7) * 64;
#pragma unroll
                for (int kw = 0; kw < 7; ++kw) {
                    float4 wa = *(const float4*)(wrow + kw * 64);
                    float4 wb = *(const float4*)(wrow + kw * 64 + 4);
#pragma unroll
                    for (int q = 0; q < 3; ++q) {
                        float xq = xv[2 * q + kw];
                        acc[0][q] = fmaf(xq, wa.x, acc[0][q]);
                        acc[1][q] = fmaf(xq, wa.y, acc[1][q]);
                        acc[2][q] = fmaf(xq, wa.z, acc[2][q]);
                        acc[3][q] = fmaf(xq, wa.w, acc[3][q]);
                        acc[4][q] = fmaf(xq, wb.x, acc[4][q]);
                        acc[5][q] = fmaf(xq, wb.y, acc[5][q]);
                        acc[6][q] = fmaf(xq, wb.z, acc[6][q]);
                        acc[7][q] = fmaf(xq, wb.w, acc[7][q]);
                    }
                }
            }
        }
    }
    int pos0 = ((ot * 18 + od) * 18 + oh) * 18 + ow0;
#pragma unroll
    for (int c = 0; c < 8; ++c)
#pragma unroll
        for (int q = 0; q < 3; ++q)
            out[(size_t)(co0 + c) * 104976 + pos0 + q] = fmaxf(acc[c][q], 0.f);
}

// ---------------- maxpool 3^4 s2 p1: (64,18^4) -> (64,9^4) f32 ----------------
__global__ void maxpool_kernel(const float* __restrict__ in, float* __restrict__ out) {
    const int T = 18, T4 = 18 * 18 * 18 * 18, O4 = 9 * 9 * 9 * 9;
    int idx = blockIdx.x * blockDim.x + threadIdx.x;
    if (idx >= 64 * O4) return;
    int co = idx / O4, p = idx % O4;
    int ow = p % 9; int t = p / 9;
    int oh = t % 9; t /= 9;
    int od = t % 9; t /= 9;
    int ot = t;
    const float* base = in + (size_t)co * T4;
    float m = -1e30f;
    for (int kt = 0; kt < 3; ++kt) { int it = 2 * ot + kt - 1; if (it < 0 || it >= T) continue;
        for (int kd = 0; kd < 3; ++kd) { int id = 2 * od + kd - 1; if (id < 0 || id >= T) continue;
            for (int kh = 0; kh < 3; ++kh) { int ih = 2 * oh + kh - 1; if (ih < 0 || ih >= T) continue;
                for (int kw = 0; kw < 3; ++kw) { int iw = 2 * ow + kw - 1; if (iw < 0 || iw >= T) continue;
                    m = fmaxf(m, base[((it * T + id) * T + ih) * T + iw]);
                }
            }
        }
    }
    out[idx] = m;
}

// ---------------- convert f32 [C][P] -> bf16 [P][C]; also zero-fills the 128-ushort zbuf ----
__global__ void cvt_pm(const float* __restrict__ in, ushortT* __restrict__ out,
                       ushortT* __restrict__ zb, int C, int Pn, int total) {
    int idx = blockIdx.x * 256 + threadIdx.x;
    if (idx < 128) zb[idx] = 0;
    if (idx >= total) return;
    int c = idx % C;
    int pos = idx / C;
    out[idx] = f2bf(in[(size_t)c * Pn + pos]);
}

// ---------------- weight prep: w f32 [3][Co][Ci][27] -> bf16 [(i*27+tap)][Co][Ci] ----------
// one block per (i, co): LDS tile transpose over (ci, tap).
__global__ void wprep(const float* __restrict__ w, ushortT* __restrict__ out, int Ci, int Co) {
    __shared__ float tile[13824]; // up to 512*27
    int i = blockIdx.x / Co, co = blockIdx.x % Co;
    const float* src = w + (size_t)(i * Co + co) * Ci * 27;
    int n = Ci * 27;
    for (int t = threadIdx.x; t < n; t += 256) tile[t] = src[t]; // tile[ci*27+tap]
    __syncthreads();
    for (int t = threadIdx.x; t < n; t += 256) {
        int tap = t / Ci, ci = t % Ci;
        out[((size_t)(i * 27 + tap) * Co + co) * Ci + ci] = f2bf(tile[ci * 27 + tap]);
    }
}

// ---------------- MFMA implicit-GEMM residual conv ----------------
// xb: bf16 [T^4][Ci]; wt: bf16 [(i*27+tap)][Co][Ci]; out bf16 [O^4][Co]
// FUSE=1: fused bias(T-valid)+res+relu epilogue. FUSE=0: write f32 partial [z][O4][Co].
template <int KC, int FUSE>
__global__ void convmfma(const ushortT* __restrict__ xb, const ushortT* __restrict__ wt,
                         const float* __restrict__ bias, const ushortT* __restrict__ res,
                         ushortT* __restrict__ outb, float* __restrict__ part,
                         const ushortT* __restrict__ zq,
                         int Ci, int Co, int T, int O, int stride, int chunk) {
    int lane = threadIdx.x & 63;
    int wv = threadIdx.x >> 6;
    int p0 = blockIdx.x * 16;
    int co0 = (blockIdx.y * 4 + wv) * 16;
    int cbase = blockIdx.z * chunk;

    int pn = p0 + (lane & 15);
    int O2 = O * O, O3 = O2 * O, O4 = O3 * O;
    bool pv = pn < O4;
    int pc = pv ? pn : 0;
    int ow = pc % O, oh = (pc / O) % O, od = (pc / O2) % O, ot = pc / O3;
    int g = lane >> 4;
    int kl = cbase + g * 8;

    const ushortT* aRow = wt + (size_t)(co0 + (lane & 15)) * Ci + kl;
    size_t tapStride = (size_t)Co * Ci;
    const ushortT* zp = zq + g * 8;

    f32x4 acc = {0.f, 0.f, 0.f, 0.f};

    int itb = ot * stride - 1, idb = od * stride - 1, ihb = oh * stride - 1, iwb = ow * stride - 1;

    for (int i = 0; i < 3; ++i) {
        int it = itb + i;
        bool vt = pv && ((unsigned)it < (unsigned)T);
        for (int kd = 0; kd < 3; ++kd) {
            int id = idb + kd;
            bool vdd = vt && ((unsigned)id < (unsigned)T);
            int btd = (it * T + id) * T;
            for (int kh = 0; kh < 3; ++kh) {
                int ih = ihb + kh;
                bool vh = vdd && ((unsigned)ih < (unsigned)T);
                for (int kw = 0; kw < 3; ++kw) {
                    int iw = iwb + kw;
                    bool v = vh && ((unsigned)iw < (unsigned)T);
                    int ip = (btd + ih) * T + iw;
                    const ushortT* bp = v ? (xb + (size_t)ip * Ci + kl) : zp;
                    int tapIdx = (i * 9 + kd * 3 + kh) * 3 + kw;
                    const ushortT* ap = aRow + (size_t)tapIdx * tapStride;
#pragma unroll
                    for (int kc = 0; kc < KC; ++kc) {
                        bf16x8 av = *(const bf16x8*)(ap + kc * 32);
                        bf16x8 bv = *(const bf16x8*)(bp + kc * 32);
                        acc = __builtin_amdgcn_mfma_f32_16x16x32_bf16(av, bv, acc, 0, 0, 0);
                    }
                }
            }
        }
    }

    if (!pv) return;
    int cob = co0 + g * 4;
    if (FUSE) {
        float bb[4] = {0.f, 0.f, 0.f, 0.f};
        for (int i = 0; i < 3; ++i) {
            int it = itb + i;
            if ((unsigned)it < (unsigned)T) {
#pragma unroll
                for (int r = 0; r < 4; ++r) bb[r] += bias[i * Co + cob + r];
            }
        }
        float rv[4] = {0.f, 0.f, 0.f, 0.f};
        if (res) {
            ushort4 rr = *(const ushort4*)(res + (size_t)pn * Co + cob);
            rv[0] = bf2f(rr.x); rv[1] = bf2f(rr.y); rv[2] = bf2f(rr.z); rv[3] = bf2f(rr.w);
        }
        ushort4 st;
        st.x = f2bf(fmaxf(acc[0] + bb[0] + rv[0], 0.f));
        st.y = f2bf(fmaxf(acc[1] + bb[1] + rv[1], 0.f));
        st.z = f2bf(fmaxf(acc[2] + bb[2] + rv[2], 0.f));
        st.w = f2bf(fmaxf(acc[3] + bb[3] + rv[3], 0.f));
        *(ushort4*)(outb + (size_t)pn * Co + cob) = st;
    } else {
        *(f32x4*)(part + ((size_t)blockIdx.z * O4 + pn) * Co + cob) = acc;
    }
}

// ---------------- finalize for k-split convs: sum partials + bias + res + relu -> bf16 -----
__global__ void finalize_k(const float* __restrict__ part, int KS,
                           const float* __restrict__ bias, const ushortT* __restrict__ res,
                           ushortT* __restrict__ outb, int Co, int O4, int T, int O, int stride,
                           int total) {
    int idx = blockIdx.x * 256 + threadIdx.x;
    if (idx >= total) return;
    int co = idx % Co;
    int pos = idx / Co;
    float v = 0.f;
    for (int z = 0; z < KS; ++z) v += part[((size_t)z * O4 + pos) * Co + co];
    int ot = pos / (O * O * O);
    for (int i = 0; i < 3; ++i) {
        int it = ot * stride + i - 1;
        if ((unsigned)it < (unsigned)T) v += bias[i * Co + co];
    }
    if (res) v += bf2f(res[idx]);
    outb[idx] = f2bf(fmaxf(v, 0.f));
}

// ---------------- downsample 1x1 conv stride2: bf16 [T^4][Ci] -> bf16 [O^4][Co] ------------
__global__ void dwconv2(const ushortT* __restrict__ x, const float* __restrict__ w,
                        ushortT* __restrict__ out, int Ci, int Co, int T, int O, int total) {
    int idx = blockIdx.x * 256 + threadIdx.x;
    if (idx >= total) return;
    int co = idx % Co;
    int pos = idx / Co;
    int O2 = O * O, O3 = O2 * O;
    int ow = pos % O, oh = (pos / O) % O, od = (pos / O2) % O, ot = pos / O3;
    int ip = (((2 * ot) * T + 2 * od) * T + 2 * oh) * T + 2 * ow;
    const ushortT* xp = x + (size_t)ip * Ci;
    const float* wp = w + (size_t)co * Ci;
    float acc = 0.f;
    for (int ci = 0; ci < Ci; ++ci) acc = fmaf(bf2f(xp[ci]), wp[ci], acc);
    out[idx] = f2bf(acc);
}

// ---------------- avgpool 2^4 + FC (512 -> 1), bf16 [16][512] input ----------------
__global__ void avgfc2(const ushortT* __restrict__ xin, const float* __restrict__ fw,
                       const float* __restrict__ fb, float* __restrict__ out) {
    __shared__ float ls[8];
    int t = threadIdx.x; // 512
    float s = 0.f;
#pragma unroll
    for (int pp = 0; pp < 16; ++pp) s += bf2f(xin[pp * 512 + t]);
    s = s * (1.f / 16.f) * fw[t];
    for (int off = 32; off > 0; off >>= 1) s += __shfl_xor(s, off, 64);
    if ((t & 63) == 0) ls[t >> 6] = s;
    __syncthreads();
    if (t == 0) {
        float tot = 0.f;
#pragma unroll
        for (int i = 0; i < 8; ++i) tot += ls[i];
        out[0] = tot + fb[0];
    }
}

extern "C" void kernel_launch(void* const* d_in, const int* in_sizes, int n_in,
                              void* d_out, int out_size, void* d_ws, size_t ws_size,
                              hipStream_t stream) {
    const float* x       = (const float*)d_in[0];
    const float* conv1_w = (const float*)d_in[1];
    const float* l1_w1 = (const float*)d_in[2];
    const float* l1_b1 = (const float*)d_in[3];
    const float* l1_w2 = (const float*)d_in[4];
    const float* l1_b2 = (const float*)d_in[5];
    const float* l2_w1 = (const float*)d_in[6];
    const float* l2_b1 = (const float*)d_in[7];
    const float* l2_w2 = (const float*)d_in[8];
    const float* l2_b2 = (const float*)d_in[9];
    const float* l2_dw = (const float*)d_in[10];
    const float* l3_w1 = (const float*)d_in[11];
    const float* l3_b1 = (const float*)d_in[12];
    const float* l3_w2 = (const float*)d_in[13];
    const float* l3_b2 = (const float*)d_in[14];
    const float* l3_dw = (const float*)d_in[15];
    const float* l4_w1 = (const float*)d_in[16];
    const float* l4_b1 = (const float*)d_in[17];
    const float* l4_w2 = (const float*)d_in[18];
    const float* l4_b2 = (const float*)d_in[19];
    const float* l4_dw = (const float*)d_in[20];
    const float* fc_w  = (const float*)d_in[21];
    const float* fc_b  = (const float*)d_in[22];
    float* outp = (float*)d_out;

    char* bp = (char*)d_ws;
    auto alloc = [&](size_t bytes) {
        char* r = bp;
        bp += (bytes + 255) & ~(size_t)255;
        return (void*)r;
    };
    float* A    = (float*)alloc(6718464ull * 4);
    float* Bp   = (float*)alloc(419904ull * 4);
    float* Wt1  = (float*)alloc(153664ull * 4);
    ushortT* X0 = (ushortT*)alloc(419904ull * 2);
    ushortT* Y1 = (ushortT*)alloc(419904ull * 2);
    ushortT* X1 = (ushortT*)alloc(419904ull * 2);
    ushortT* Y2 = (ushortT*)alloc(80000ull * 2);
    ushortT* R2 = (ushortT*)alloc(80000ull * 2);
    ushortT* X2 = (ushortT*)alloc(80000ull * 2);
    ushortT* Y3 = (ushortT*)alloc(20736ull * 2);
    ushortT* R3 = (ushortT*)alloc(20736ull * 2);
    ushortT* X3 = (ushortT*)alloc(20736ull * 2);
    ushortT* Y4 = (ushortT*)alloc(8192ull * 2);
    ushortT* R4 = (ushortT*)alloc(8192ull * 2);
    ushortT* X4 = (ushortT*)alloc(8192ull * 2);
    ushortT* W11 = (ushortT*)alloc(331776ull * 2);
    ushortT* W12 = (ushortT*)alloc(331776ull * 2);
    ushortT* W21 = (ushortT*)alloc(663552ull * 2);
    ushortT* W22 = (ushortT*)alloc(1327104ull * 2);
    ushortT* W31 = (ushortT*)alloc(2654208ull * 2);
    ushortT* W32 = (ushortT*)alloc(5308416ull * 2);
    ushortT* W41 = (ushortT*)alloc(10616832ull * 2);
    ushortT* W42 = (ushortT*)alloc(21233664ull * 2);
    float* P    = (float*)alloc(82944ull * 4);
    ushortT* ZB = (ushortT*)alloc(256);
    if ((size_t)(bp - (char*)d_ws) > ws_size) return; // workspace too small: fail cleanly

    // ---- weight preparation ----
    wprep<<<192,  256, 0, stream>>>(l1_w1, W11, 64, 64);
    wprep<<<192,  256, 0, stream>>>(l1_w2, W12, 64, 64);
    wprep<<<384,  256, 0, stream>>>(l2_w1, W21, 64, 128);
    wprep<<<384,  256, 0, stream>>>(l2_w2, W22, 128, 128);
    wprep<<<768,  256, 0, stream>>>(l3_w1, W31, 128, 256);
    wprep<<<768,  256, 0, stream>>>(l3_w2, W32, 256, 256);
    wprep<<<1536, 256, 0, stream>>>(l4_w1, W41, 256, 512);
    wprep<<<1536, 256, 0, stream>>>(l4_w2, W42, 512, 512);
    transpose_bk<<<dim3(11, 2, 7), dim3(32, 8), 0, stream>>>(conv1_w, Wt1, 64, 343);

    // ---- stem ----
    conv1_kernel2<<<dim3(137, 8), 256, 0, stream>>>(x, Wt1, A);
    maxpool_kernel<<<(64 * 6561 + 255) / 256, 256, 0, stream>>>(A, Bp);
    cvt_pm<<<(419904 + 255) / 256, 256, 0, stream>>>(Bp, X0, ZB, 64, 6561, 419904);

    // ---- layer1: 64->64, T=9, s1, identity residual ----
    convmfma<2, 1><<<dim3(411, 1, 1), 256, 0, stream>>>(X0, W11, l1_b1, nullptr, Y1, nullptr,
                                                        ZB, 64, 64, 9, 9, 1, 64);
    convmfma<2, 1><<<dim3(411, 1, 1), 256, 0, stream>>>(Y1, W12, l1_b2, X0, X1, nullptr,
                                                        ZB, 64, 64, 9, 9, 1, 64);

    // ---- layer2: 64->128, 9->5, s2 ----
    dwconv2<<<(80000 + 255) / 256, 256, 0, stream>>>(X1, l2_dw, R2, 64, 128, 9, 5, 80000);
    convmfma<2, 1><<<dim3(40, 2, 1), 256, 0, stream>>>(X1, W21, l2_b1, nullptr, Y2, nullptr,
                                                       ZB, 64, 128, 9, 5, 2, 64);
    convmfma<4, 1><<<dim3(40, 2, 1), 256, 0, stream>>>(Y2, W22, l2_b2, R2, X2, nullptr,
                                                       ZB, 128, 128, 5, 5, 1, 128);

    // ---- layer3: 128->256, 5->3, s2 (ci-split KS=4) ----
    dwconv2<<<(20736 + 255) / 256, 256, 0, stream>>>(X2, l3_dw, R3, 128, 256, 5, 3, 20736);
    convmfma<1, 0><<<dim3(6, 4, 4), 256, 0, stream>>>(X2, W31, nullptr, nullptr, nullptr, P,
                                                      ZB, 128, 256, 5, 3, 2, 32);
    finalize_k<<<(20736 + 255) / 256, 256, 0, stream>>>(P, 4, l3_b1, nullptr, Y3, 256, 81,
                                                        5, 3, 2, 20736);
    convmfma<2, 0><<<dim3(6, 4, 4), 256, 0, stream>>>(Y3, W32, nullptr, nullptr, nullptr, P,
                                                      ZB, 256, 256, 3, 3, 1, 64);
    finalize_k<<<(20736 + 255) / 256, 256, 0, stream>>>(P, 4, l3_b2, R3, X3, 256, 81,
                                                        3, 3, 1, 20736);

    // ---- layer4: 256->512, 3->2, s2 (ci-split KS=8) ----
    dwconv2<<<(8192 + 255) / 256, 256, 0, stream>>>(X3, l4_dw, R4, 256, 512, 3, 2, 8192);
    convmfma<1, 0><<<dim3(1, 8, 8), 256, 0, stream>>>(X3, W41, nullptr, nullptr, nullptr, P,
                                                      ZB, 256, 512, 3, 2, 2, 32);
    finalize_k<<<(8192 + 255) / 256, 256, 0, stream>>>(P, 8, l4_b1, nullptr, Y4, 512, 16,
                                                       3, 2, 2, 8192);
    convmfma<2, 0><<<dim3(1, 8, 8), 256, 0, stream>>>(Y4, W42, nullptr, nullptr, nullptr, P,
                                                      ZB, 512, 512, 2, 2, 1, 64);
    finalize_k<<<(8192 + 255) / 256, 256, 0, stream>>>(P, 8, l4_b2, R4, X4, 512, 16,
                                                       2, 2, 1, 8192);

    // ---- head ----
    avgfc2<<<1, 512, 0, stream>>>(X4, fc_w, fc_b, outp);
}

// Round 4
// 800.522 us; speedup vs baseline: 10.1412x; 2.7127x over previous
//
#include <hip/hip_runtime.h>

typedef __bf16 bf16x8 __attribute__((ext_vector_type(8)));
typedef float f32x4 __attribute__((ext_vector_type(4)));
typedef unsigned short ushortT;

__device__ __forceinline__ int imin(int a, int b) { return a < b ? a : b; }
__device__ __forceinline__ int imax(int a, int b) { return a > b ? a : b; }

__device__ __forceinline__ unsigned short f2bf(float f) {
    unsigned u = __float_as_uint(f);
    u += 0x7fffu + ((u >> 16) & 1u);
    return (unsigned short)(u >> 16);
}
__device__ __forceinline__ float bf2f(unsigned short h) {
    return __uint_as_float((unsigned)h << 16);
}

// ---------------- conv1 weight prep: (7,64,1,7,7,7) f32 -> bf16 [co][3136] ----------------
// k = (kt*7+kd)*64 + kh*8 + kw, kh/kw padded to 8 (pad slots = 0).
__global__ void wprep1(const float* __restrict__ w, ushortT* __restrict__ out) {
    int idx = blockIdx.x * 256 + threadIdx.x; // 64*3136 = 200704
    if (idx >= 200704) return;
    int k = idx % 3136, co = idx / 3136;
    int kw = k & 7, kh = (k >> 3) & 7, kdt = k >> 6;
    int kt = kdt / 7, kd = kdt % 7;
    float v = 0.f;
    if (kh < 7 && kw < 7)
        v = w[(size_t)(kt * 64 + co) * 343 + kd * 49 + kh * 7 + kw];
    out[idx] = f2bf(v);
}

// ---------------- conv1 via MFMA implicit im2col ----------------
// out f32 [64][18^4], block = 64co x 64pos (tile 1x4x4x4), 4 waves.
// LDS x tile dims (lt,ld,lh,lw) = (7,13,14,16), addr = ((lt*13+ld)*14+lh)*16+lw.
__global__ __launch_bounds__(256) void conv1_mfma(const float* __restrict__ x,
                                                  const ushortT* __restrict__ aw,
                                                  float* __restrict__ out) {
    __shared__ ushortT xs[20384];
    int bid = blockIdx.x;
    int wt = bid % 5; int rest = bid / 5;
    int ht = rest % 5; rest /= 5;
    int dt = rest % 5; int ot = rest / 5; // 18*5*5*5 = 2250 blocks
    int ow0 = wt * 4, oh0 = ht * 4, od0 = dt * 4;
    int it0 = 2 * ot - 3, id0 = 2 * od0 - 3, ih0 = 2 * oh0 - 3, iw0 = 2 * ow0 - 3;

    int tid = threadIdx.x;
    // stage x region (zero-filled outside bounds; all values finite)
    for (int e = tid; e < 5096; e += 256) {
        int lwq = e & 3; int r2 = e >> 2;
        int lh = r2 % 14; r2 /= 14;
        int ld = r2 % 13; int lt = r2 / 13;
        int gt = it0 + lt, gd = id0 + ld, gh = ih0 + lh;
        int gwb = iw0 + lwq * 4;
        bool rowok = ((unsigned)gt < 36u) && ((unsigned)gd < 36u) && ((unsigned)gh < 36u);
        const float* xrow = x + (((size_t)gt * 36 + gd) * 36 + gh) * 36;
        ushort4 v;
        unsigned short* pv = (unsigned short*)&v;
#pragma unroll
        for (int q = 0; q < 4; ++q) {
            int gw = gwb + q;
            float f = (rowok && (unsigned)gw < 36u) ? xrow[gw] : 0.f;
            pv[q] = f2bf(f);
        }
        *(ushort4*)(xs + e * 4) = v;
    }
    __syncthreads();

    int lane = tid & 63, wv = tid >> 6;
    int l15 = lane & 15, g = lane >> 4;
    int dh = (l15 >> 2) & 3, dw = l15 & 3;
    int base0 = dh * 32 + dw * 2 + g * 16;

    const ushortT* ap = aw + (size_t)(wv * 16 + l15) * 3136 + g * 8;
    f32x4 acc[4];
#pragma unroll
    for (int m = 0; m < 4; ++m) acc[m] = (f32x4){0.f, 0.f, 0.f, 0.f};

    for (int kt = 0; kt < 7; ++kt) {
        int kbase = base0 + kt * 2912;
#pragma unroll
        for (int kd = 0; kd < 7; ++kd) {
#pragma unroll
            for (int khq = 0; khq < 2; ++khq) {
                bf16x8 av = *(const bf16x8*)ap; ap += 32;
                int toff = kbase + kd * 224 + khq * 64;
#pragma unroll
                for (int m = 0; m < 4; ++m) {
                    int off = toff + m * 448;
                    union { unsigned u[4]; bf16x8 v; } bb;
                    bb.u[0] = *(const unsigned*)(xs + off);
                    bb.u[1] = *(const unsigned*)(xs + off + 2);
                    bb.u[2] = *(const unsigned*)(xs + off + 4);
                    bb.u[3] = *(const unsigned*)(xs + off + 6);
                    acc[m] = __builtin_amdgcn_mfma_f32_16x16x32_bf16(av, bb.v, acc[m], 0, 0, 0);
                }
            }
        }
    }

    int oh = oh0 + dh, ow = ow0 + dw;
    if (oh < 18 && ow < 18) {
#pragma unroll
        for (int m = 0; m < 4; ++m) {
            int od = od0 + m;
            if (od < 18) {
                int pidx = ((ot * 18 + od) * 18 + oh) * 18 + ow;
#pragma unroll
                for (int r = 0; r < 4; ++r) {
                    int co = wv * 16 + g * 4 + r;
                    out[(size_t)co * 104976 + pidx] = fmaxf(acc[m][r], 0.f);
                }
            }
        }
    }
}

// ---------------- maxpool 3^4 s2 p1: (64,18^4) -> (64,9^4) f32 ----------------
__global__ void maxpool_kernel(const float* __restrict__ in, float* __restrict__ out) {
    const int T = 18, T4 = 18 * 18 * 18 * 18, O4 = 9 * 9 * 9 * 9;
    int idx = blockIdx.x * blockDim.x + threadIdx.x;
    if (idx >= 64 * O4) return;
    int co = idx / O4, p = idx % O4;
    int ow = p % 9; int t = p / 9;
    int oh = t % 9; t /= 9;
    int od = t % 9; t /= 9;
    int ot = t;
    const float* base = in + (size_t)co * T4;
    float m = -1e30f;
    for (int kt = 0; kt < 3; ++kt) { int it = 2 * ot + kt - 1; if (it < 0 || it >= T) continue;
        for (int kd = 0; kd < 3; ++kd) { int id = 2 * od + kd - 1; if (id < 0 || id >= T) continue;
            for (int kh = 0; kh < 3; ++kh) { int ih = 2 * oh + kh - 1; if (ih < 0 || ih >= T) continue;
                for (int kw = 0; kw < 3; ++kw) { int iw = 2 * ow + kw - 1; if (iw < 0 || iw >= T) continue;
                    m = fmaxf(m, base[((it * T + id) * T + ih) * T + iw]);
                }
            }
        }
    }
    out[idx] = m;
}

// ---------------- convert f32 [C][P] -> bf16 [P][C]; also zero-fills the 128-ushort zbuf ----
__global__ void cvt_pm(const float* __restrict__ in, ushortT* __restrict__ out,
                       ushortT* __restrict__ zb, int C, int Pn, int total) {
    int idx = blockIdx.x * 256 + threadIdx.x;
    if (idx < 128) zb[idx] = 0;
    if (idx >= total) return;
    int c = idx % C;
    int pos = idx / C;
    out[idx] = f2bf(in[(size_t)c * Pn + pos]);
}

// ---------------- weight prep: w f32 [3][Co][Ci][27] -> bf16 [(i*27+tap)][Co][Ci] ----------
__global__ void wprep(const float* __restrict__ w, ushortT* __restrict__ out, int Ci, int Co) {
    __shared__ float tile[13824]; // up to 512*27
    int i = blockIdx.x / Co, co = blockIdx.x % Co;
    const float* src = w + (size_t)(i * Co + co) * Ci * 27;
    int n = Ci * 27;
    for (int t = threadIdx.x; t < n; t += 256) tile[t] = src[t]; // tile[ci*27+tap]
    __syncthreads();
    for (int t = threadIdx.x; t < n; t += 256) {
        int tap = t / Ci, ci = t % Ci;
        out[((size_t)(i * 27 + tap) * Co + co) * Ci + ci] = f2bf(tile[ci * 27 + tap]);
    }
}

// ---------------- MFMA implicit-GEMM residual conv ----------------
template <int KC, int FUSE>
__global__ void convmfma(const ushortT* __restrict__ xb, const ushortT* __restrict__ wt,
                         const float* __restrict__ bias, const ushortT* __restrict__ res,
                         ushortT* __restrict__ outb, float* __restrict__ part,
                         const ushortT* __restrict__ zq,
                         int Ci, int Co, int T, int O, int stride, int chunk) {
    int lane = threadIdx.x & 63;
    int wv = threadIdx.x >> 6;
    int p0 = blockIdx.x * 16;
    int co0 = (blockIdx.y * 4 + wv) * 16;
    int cbase = blockIdx.z * chunk;

    int pn = p0 + (lane & 15);
    int O2 = O * O, O3 = O2 * O, O4 = O3 * O;
    bool pv = pn < O4;
    int pc = pv ? pn : 0;
    int ow = pc % O, oh = (pc / O) % O, od = (pc / O2) % O, ot = pc / O3;
    int g = lane >> 4;
    int kl = cbase + g * 8;

    const ushortT* aRow = wt + (size_t)(co0 + (lane & 15)) * Ci + kl;
    size_t tapStride = (size_t)Co * Ci;
    const ushortT* zp = zq + g * 8;

    f32x4 acc = {0.f, 0.f, 0.f, 0.f};

    int itb = ot * stride - 1, idb = od * stride - 1, ihb = oh * stride - 1, iwb = ow * stride - 1;

    for (int i = 0; i < 3; ++i) {
        int it = itb + i;
        bool vt = pv && ((unsigned)it < (unsigned)T);
        for (int kd = 0; kd < 3; ++kd) {
            int id = idb + kd;
            bool vdd = vt && ((unsigned)id < (unsigned)T);
            int btd = (it * T + id) * T;
            for (int kh = 0; kh < 3; ++kh) {
                int ih = ihb + kh;
                bool vh = vdd && ((unsigned)ih < (unsigned)T);
                for (int kw = 0; kw < 3; ++kw) {
                    int iw = iwb + kw;
                    bool v = vh && ((unsigned)iw < (unsigned)T);
                    int ip = (btd + ih) * T + iw;
                    const ushortT* bp = v ? (xb + (size_t)ip * Ci + kl) : zp;
                    int tapIdx = (i * 9 + kd * 3 + kh) * 3 + kw;
                    const ushortT* apw = aRow + (size_t)tapIdx * tapStride;
#pragma unroll
                    for (int kc = 0; kc < KC; ++kc) {
                        bf16x8 av = *(const bf16x8*)(apw + kc * 32);
                        bf16x8 bv = *(const bf16x8*)(bp + kc * 32);
                        acc = __builtin_amdgcn_mfma_f32_16x16x32_bf16(av, bv, acc, 0, 0, 0);
                    }
                }
            }
        }
    }

    if (!pv) return;
    int cob = co0 + g * 4;
    if (FUSE) {
        float bb[4] = {0.f, 0.f, 0.f, 0.f};
        for (int i = 0; i < 3; ++i) {
            int it = itb + i;
            if ((unsigned)it < (unsigned)T) {
#pragma unroll
                for (int r = 0; r < 4; ++r) bb[r] += bias[i * Co + cob + r];
            }
        }
        float rv[4] = {0.f, 0.f, 0.f, 0.f};
        if (res) {
            ushort4 rr = *(const ushort4*)(res + (size_t)pn * Co + cob);
            rv[0] = bf2f(rr.x); rv[1] = bf2f(rr.y); rv[2] = bf2f(rr.z); rv[3] = bf2f(rr.w);
        }
        ushort4 st;
        st.x = f2bf(fmaxf(acc[0] + bb[0] + rv[0], 0.f));
        st.y = f2bf(fmaxf(acc[1] + bb[1] + rv[1], 0.f));
        st.z = f2bf(fmaxf(acc[2] + bb[2] + rv[2], 0.f));
        st.w = f2bf(fmaxf(acc[3] + bb[3] + rv[3], 0.f));
        *(ushort4*)(outb + (size_t)pn * Co + cob) = st;
    } else {
        *(f32x4*)(part + ((size_t)blockIdx.z * O4 + pn) * Co + cob) = acc;
    }
}

// ---------------- finalize for k-split convs ----------------
__global__ void finalize_k(const float* __restrict__ part, int KS,
                           const float* __restrict__ bias, const ushortT* __restrict__ res,
                           ushortT* __restrict__ outb, int Co, int O4, int T, int O, int stride,
                           int total) {
    int idx = blockIdx.x * 256 + threadIdx.x;
    if (idx >= total) return;
    int co = idx % Co;
    int pos = idx / Co;
    float v = 0.f;
    for (int z = 0; z < KS; ++z) v += part[((size_t)z * O4 + pos) * Co + co];
    int ot = pos / (O * O * O);
    for (int i = 0; i < 3; ++i) {
        int it = ot * stride + i - 1;
        if ((unsigned)it < (unsigned)T) v += bias[i * Co + co];
    }
    if (res) v += bf2f(res[idx]);
    outb[idx] = f2bf(fmaxf(v, 0.f));
}

// ---------------- downsample 1x1 conv stride2 ----------------
__global__ void dwconv2(const ushortT* __restrict__ x, const float* __restrict__ w,
                        ushortT* __restrict__ out, int Ci, int Co, int T, int O, int total) {
    int idx = blockIdx.x * 256 + threadIdx.x;
    if (idx >= total) return;
    int co = idx % Co;
    int pos = idx / Co;
    int O2 = O * O, O3 = O2 * O;
    int ow = pos % O, oh = (pos / O) % O, od = (pos / O2) % O, ot = pos / O3;
    int ip = (((2 * ot) * T + 2 * od) * T + 2 * oh) * T + 2 * ow;
    const ushortT* xp = x + (size_t)ip * Ci;
    const float* wp = w + (size_t)co * Ci;
    float acc = 0.f;
    for (int ci = 0; ci < Ci; ++ci) acc = fmaf(bf2f(xp[ci]), wp[ci], acc);
    out[idx] = f2bf(acc);
}

// ---------------- avgpool 2^4 + FC (512 -> 1) ----------------
__global__ void avgfc2(const ushortT* __restrict__ xin, const float* __restrict__ fw,
                       const float* __restrict__ fb, float* __restrict__ out) {
    __shared__ float ls[8];
    int t = threadIdx.x; // 512
    float s = 0.f;
#pragma unroll
    for (int pp = 0; pp < 16; ++pp) s += bf2f(xin[pp * 512 + t]);
    s = s * (1.f / 16.f) * fw[t];
    for (int off = 32; off > 0; off >>= 1) s += __shfl_xor(s, off, 64);
    if ((t & 63) == 0) ls[t >> 6] = s;
    __syncthreads();
    if (t == 0) {
        float tot = 0.f;
#pragma unroll
        for (int i = 0; i < 8; ++i) tot += ls[i];
        out[0] = tot + fb[0];
    }
}

extern "C" void kernel_launch(void* const* d_in, const int* in_sizes, int n_in,
                              void* d_out, int out_size, void* d_ws, size_t ws_size,
                              hipStream_t stream) {
    const float* x       = (const float*)d_in[0];
    const float* conv1_w = (const float*)d_in[1];
    const float* l1_w1 = (const float*)d_in[2];
    const float* l1_b1 = (const float*)d_in[3];
    const float* l1_w2 = (const float*)d_in[4];
    const float* l1_b2 = (const float*)d_in[5];
    const float* l2_w1 = (const float*)d_in[6];
    const float* l2_b1 = (const float*)d_in[7];
    const float* l2_w2 = (const float*)d_in[8];
    const float* l2_b2 = (const float*)d_in[9];
    const float* l2_dw = (const float*)d_in[10];
    const float* l3_w1 = (const float*)d_in[11];
    const float* l3_b1 = (const float*)d_in[12];
    const float* l3_w2 = (const float*)d_in[13];
    const float* l3_b2 = (const float*)d_in[14];
    const float* l3_dw = (const float*)d_in[15];
    const float* l4_w1 = (const float*)d_in[16];
    const float* l4_b1 = (const float*)d_in[17];
    const float* l4_w2 = (const float*)d_in[18];
    const float* l4_b2 = (const float*)d_in[19];
    const float* l4_dw = (const float*)d_in[20];
    const float* fc_w  = (const float*)d_in[21];
    const float* fc_b  = (const float*)d_in[22];
    float* outp = (float*)d_out;

    char* bp = (char*)d_ws;
    auto alloc = [&](size_t bytes) {
        char* r = bp;
        bp += (bytes + 255) & ~(size_t)255;
        return (void*)r;
    };
    float* A    = (float*)alloc(6718464ull * 4);
    float* Bp   = (float*)alloc(419904ull * 4);
    ushortT* Aw1 = (ushortT*)alloc(200704ull * 2);
    ushortT* X0 = (ushortT*)alloc(419904ull * 2);
    ushortT* Y1 = (ushortT*)alloc(419904ull * 2);
    ushortT* X1 = (ushortT*)alloc(419904ull * 2);
    ushortT* Y2 = (ushortT*)alloc(80000ull * 2);
    ushortT* R2 = (ushortT*)alloc(80000ull * 2);
    ushortT* X2 = (ushortT*)alloc(80000ull * 2);
    ushortT* Y3 = (ushortT*)alloc(20736ull * 2);
    ushortT* R3 = (ushortT*)alloc(20736ull * 2);
    ushortT* X3 = (ushortT*)alloc(20736ull * 2);
    ushortT* Y4 = (ushortT*)alloc(8192ull * 2);
    ushortT* R4 = (ushortT*)alloc(8192ull * 2);
    ushortT* X4 = (ushortT*)alloc(8192ull * 2);
    ushortT* W11 = (ushortT*)alloc(331776ull * 2);
    ushortT* W12 = (ushortT*)alloc(331776ull * 2);
    ushortT* W21 = (ushortT*)alloc(663552ull * 2);
    ushortT* W22 = (ushortT*)alloc(1327104ull * 2);
    ushortT* W31 = (ushortT*)alloc(2654208ull * 2);
    ushortT* W32 = (ushortT*)alloc(5308416ull * 2);
    ushortT* W41 = (ushortT*)alloc(10616832ull * 2);
    ushortT* W42 = (ushortT*)alloc(21233664ull * 2);
    float* P    = (float*)alloc(82944ull * 4);
    ushortT* ZB = (ushortT*)alloc(256);
    if ((size_t)(bp - (char*)d_ws) > ws_size) return; // workspace too small: fail cleanly

    // ---- weight preparation ----
    wprep1<<<784, 256, 0, stream>>>(conv1_w, Aw1);
    wprep<<<192,  256, 0, stream>>>(l1_w1, W11, 64, 64);
    wprep<<<192,  256, 0, stream>>>(l1_w2, W12, 64, 64);
    wprep<<<384,  256, 0, stream>>>(l2_w1, W21, 64, 128);
    wprep<<<384,  256, 0, stream>>>(l2_w2, W22, 128, 128);
    wprep<<<768,  256, 0, stream>>>(l3_w1, W31, 128, 256);
    wprep<<<768,  256, 0, stream>>>(l3_w2, W32, 256, 256);
    wprep<<<1536, 256, 0, stream>>>(l4_w1, W41, 256, 512);
    wprep<<<1536, 256, 0, stream>>>(l4_w2, W42, 512, 512);

    // ---- stem ----
    conv1_mfma<<<2250, 256, 0, stream>>>(x, Aw1, A);
    maxpool_kernel<<<(64 * 6561 + 255) / 256, 256, 0, stream>>>(A, Bp);
    cvt_pm<<<(419904 + 255) / 256, 256, 0, stream>>>(Bp, X0, ZB, 64, 6561, 419904);

    // ---- layer1: 64->64, T=9, s1, identity residual ----
    convmfma<2, 1><<<dim3(411, 1, 1), 256, 0, stream>>>(X0, W11, l1_b1, nullptr, Y1, nullptr,
                                                        ZB, 64, 64, 9, 9, 1, 64);
    convmfma<2, 1><<<dim3(411, 1, 1), 256, 0, stream>>>(Y1, W12, l1_b2, X0, X1, nullptr,
                                                        ZB, 64, 64, 9, 9, 1, 64);

    // ---- layer2: 64->128, 9->5, s2 ----
    dwconv2<<<(80000 + 255) / 256, 256, 0, stream>>>(X1, l2_dw, R2, 64, 128, 9, 5, 80000);
    convmfma<2, 1><<<dim3(40, 2, 1), 256, 0, stream>>>(X1, W21, l2_b1, nullptr, Y2, nullptr,
                                                       ZB, 64, 128, 9, 5, 2, 64);
    convmfma<4, 1><<<dim3(40, 2, 1), 256, 0, stream>>>(Y2, W22, l2_b2, R2, X2, nullptr,
                                                       ZB, 128, 128, 5, 5, 1, 128);

    // ---- layer3: 128->256, 5->3, s2 (ci-split KS=4) ----
    dwconv2<<<(20736 + 255) / 256, 256, 0, stream>>>(X2, l3_dw, R3, 128, 256, 5, 3, 20736);
    convmfma<1, 0><<<dim3(6, 4, 4), 256, 0, stream>>>(X2, W31, nullptr, nullptr, nullptr, P,
                                                      ZB, 128, 256, 5, 3, 2, 32);
    finalize_k<<<(20736 + 255) / 256, 256, 0, stream>>>(P, 4, l3_b1, nullptr, Y3, 256, 81,
                                                        5, 3, 2, 20736);
    convmfma<2, 0><<<dim3(6, 4, 4), 256, 0, stream>>>(Y3, W32, nullptr, nullptr, nullptr, P,
                                                      ZB, 256, 256, 3, 3, 1, 64);
    finalize_k<<<(20736 + 255) / 256, 256, 0, stream>>>(P, 4, l3_b2, R3, X3, 256, 81,
                                                        3, 3, 1, 20736);

    // ---- layer4: 256->512, 3->2, s2 (ci-split KS=8) ----
    dwconv2<<<(8192 + 255) / 256, 256, 0, stream>>>(X3, l4_dw, R4, 256, 512, 3, 2, 8192);
    convmfma<1, 0><<<dim3(1, 8, 8), 256, 0, stream>>>(X3, W41, nullptr, nullptr, nullptr, P,
                                                      ZB, 256, 512, 3, 2, 2, 32);
    finalize_k<<<(8192 + 255) / 256, 256, 0, stream>>>(P, 8, l4_b1, nullptr, Y4, 512, 16,
                                                       3, 2, 2, 8192);
    convmfma<2, 0><<<dim3(1, 8, 8), 256, 0, stream>>>(Y4, W42, nullptr, nullptr, nullptr, P,
                                                      ZB, 512, 512, 2, 2, 1, 64);
    finalize_k<<<(8192 + 255) / 256, 256, 0, stream>>>(P, 8, l4_b2, R4, X4, 512, 16,
                                                       2, 2, 1, 8192);

    // ---- head ----
    avgfc2<<<1, 512, 0, stream>>>(X4, fc_w, fc_b, outp);
}